// Round 12
// baseline (88.865 us; speedup 1.0000x reference)
//
#include <hip/hip_runtime.h>
#include <cstddef>
#include <cstdint>

typedef short bf16x8 __attribute__((ext_vector_type(8)));
typedef float f32x4 __attribute__((ext_vector_type(4)));

#define Bsz 256
#define Dsz 512
#define Gsz 64
#define Ksz 512

// ws float offsets
#define WS_DFLAT 0         // [512][256] f32
#define WS_SOFTS 131072    // [256][512] f32 (b-major, flat-k)
#define WS_BNORM 278528    // [256]
#define WS_CNORM 278784    // [512]
#define WS_PSB   279296    // [256][64] bf16, normal [b][g] order
#define WS_ONB   287488    // 2 planes [512][512] bf16
#define WS_ZB    549632    // 2 planes [256][512] bf16
#define WS_S     680704    // S tiles: [bid 2048][8192 us] = 33.5 MB (R6 proved ws fits)

#define ONB_STRIDE 262144  // ushorts per plane
#define ZB_STRIDE  131072  // ushorts per plane

// out float offsets
#define OUT_QMU  0
#define OUT_QSIG 33554432
#define OUT_DBG  67108864
#define OUT_DIST 67125248

__device__ __forceinline__ unsigned short f2bf(float f) {
  unsigned int u = __float_as_uint(f);
  u = (u + 0x7FFFu + ((u >> 16) & 1u)) >> 16;
  return (unsigned short)u;
}
__device__ __forceinline__ float bf2f(unsigned short h) {
  return __uint_as_float(((unsigned int)h) << 16);
}

// ---------- K1: prep (proven R2/R4/R7) ----------
__global__ __launch_bounds__(256) void k_prep(const float* __restrict__ mu,
                                              const float* __restrict__ ls,
                                              const float* __restrict__ on,
                                              float* __restrict__ ws) {
  int t = threadIdx.x;
  __shared__ float red[256];
  if (blockIdx.x < 512) {
    int k = blockIdx.x;
    float4 v = *(const float4*)(on + (size_t)k * 1024 + 4 * t);
    unsigned short* onb0 = (unsigned short*)(ws + WS_ONB);
    unsigned short* onb1 = onb0 + ONB_STRIDE;
    *(ushort2*)&onb0[(size_t)k * 512 + 2 * t] = make_ushort2(f2bf(v.x), f2bf(v.z));
    *(ushort2*)&onb1[(size_t)k * 512 + 2 * t] = make_ushort2(f2bf(v.y), f2bf(v.w));
    red[t] = v.x * v.x + v.y * v.y + v.z * v.z + v.w * v.w;
    __syncthreads();
    for (int off = 128; off > 0; off >>= 1) {
      if (t < off) red[t] += red[t + off];
      __syncthreads();
    }
    if (t == 0) ws[WS_CNORM + k] = red[0];
  } else {
    int b = blockIdx.x - 512;
    unsigned short* zb0 = (unsigned short*)(ws + WS_ZB);
    unsigned short* zb1 = zb0 + ZB_STRIDE;
    float part = 0.f;
    for (int d = t; d < Dsz; d += 256) {
      float m = mu[b * Dsz + d];
      float s = expf(ls[b * Dsz + d]);
      zb0[(size_t)b * 512 + d] = f2bf(m);
      zb1[(size_t)b * 512 + d] = f2bf(s);
      part += m * m + s * s;
    }
    red[t] = part;
    __syncthreads();
    for (int off = 128; off > 0; off >>= 1) {
      if (t < off) red[t] += red[t + off];
      __syncthreads();
    }
    if (t == 0) ws[WS_BNORM + b] = red[0];
  }
}

// ---------- K2: d_kb via bf16 MFMA (proven R4/R7) ----------
__global__ __launch_bounds__(256) void k_dkb(float* __restrict__ ws,
                                             float* __restrict__ out) {
  __shared__ float pl[4][16][33];
  int t = threadIdx.x, l = t & 63, w = t >> 6;
  int lr = l & 15, lh = l >> 4;
  if (blockIdx.x == 0) out[OUT_DIST + t] = 0.f;
  int kt = blockIdx.x >> 3, bt = blockIdx.x & 7;
  int k0 = kt * 16, b0 = bt * 32;
  const unsigned short* Ap =
      (const unsigned short*)(ws + WS_ONB) + (size_t)(w >> 1) * ONB_STRIDE + (size_t)k0 * 512;
  const unsigned short* Bp =
      (const unsigned short*)(ws + WS_ZB) + (size_t)(w >> 1) * ZB_STRIDE + (size_t)b0 * 512;
  int dbase = (w & 1) * 256;

  f32x4 acc[2];
#pragma unroll
  for (int j = 0; j < 2; ++j) { acc[j][0] = 0.f; acc[j][1] = 0.f; acc[j][2] = 0.f; acc[j][3] = 0.f; }

#pragma unroll
  for (int kk = 0; kk < 8; ++kk) {
    int dl = dbase + kk * 32 + lh * 8;
    bf16x8 a0 = *(const bf16x8*)(Ap + (size_t)lr * 512 + dl);
    bf16x8 q0 = *(const bf16x8*)(Bp + (size_t)lr * 512 + dl);
    bf16x8 q1 = *(const bf16x8*)(Bp + (size_t)(lr + 16) * 512 + dl);
    acc[0] = __builtin_amdgcn_mfma_f32_16x16x32_bf16(a0, q0, acc[0], 0, 0, 0);
    acc[1] = __builtin_amdgcn_mfma_f32_16x16x32_bf16(a0, q1, acc[1], 0, 0, 0);
  }

#pragma unroll
  for (int j = 0; j < 2; ++j)
#pragma unroll
    for (int r = 0; r < 4; ++r)
      pl[w][lh * 4 + r][j * 16 + lr] = acc[j][r];
  __syncthreads();

  int r = t >> 4, c = (t & 15) * 2;
  float s0 = pl[0][r][c] + pl[1][r][c] + pl[2][r][c] + pl[3][r][c];
  float s1 = pl[0][r][c + 1] + pl[1][r][c + 1] + pl[2][r][c + 1] + pl[3][r][c + 1];
  float cn = ws[WS_CNORM + k0 + r];
  float2 o = make_float2(cn + ws[WS_BNORM + b0 + c] - 2.f * s0,
                         cn + ws[WS_BNORM + b0 + c + 1] - 2.f * s1);
  *(float2*)&ws[WS_DFLAT + (size_t)(k0 + r) * 256 + b0 + c] = o;
}

// ---------- K3: fused softmaxes + dist atomics (proven R7) ----------
__global__ __launch_bounds__(256) void k_sm(float* __restrict__ ws,
                                            float* __restrict__ out) {
  int g = blockIdx.x, t = threadIdx.x;
  const float* df = ws + WS_DFLAT;
  int k = 2 * t + (g >> 5);
  int col = (g & 31) << 3;
  const float* p = df + (size_t)k * 256 + col;
  float4 v0 = *(const float4*)p;
  float4 v1 = *(const float4*)(p + 4);
  float d[8] = {v0.x, v0.y, v0.z, v0.w, v1.x, v1.y, v1.z, v1.w};
  float m = d[0];
#pragma unroll
  for (int n = 1; n < 8; ++n) m = fminf(m, d[n]);
  float wv[8], s = 0.f, wd = 0.f;
#pragma unroll
  for (int n = 0; n < 8; ++n) {
    wv[n] = expf(m - d[n]);
    s += wv[n];
    wd += wv[n] * d[n];
  }
  float inv = 1.f / s;
  float* so = ws + WS_SOFTS + (size_t)t * 512 + g * 8;
  *(float4*)so = make_float4(wv[0] * inv, wv[1] * inv, wv[2] * inv, wv[3] * inv);
  *(float4*)(so + 4) = make_float4(wv[4] * inv, wv[5] * inv, wv[6] * inv, wv[7] * inv);
  float dbg = wd * inv;
  out[OUT_DBG + t * 64 + g] = dbg;

  __shared__ float red[256];
  red[t] = dbg;
  __syncthreads();
  for (int off = 128; off > 0; off >>= 1) {
    if (t < off) red[t] = fminf(red[t], red[t + off]);
    __syncthreads();
  }
  float mm = red[0];
  __syncthreads();
  float wp = expf(mm - dbg);
  red[t] = wp;
  __syncthreads();
  for (int off = 128; off > 0; off >>= 1) {
    if (t < off) red[t] += red[t + off];
    __syncthreads();
  }
  float psv = wp / red[0];
  ((unsigned short*)(ws + WS_PSB))[t * 64 + g] = f2bf(psv);
  atomicAdd(&out[OUT_DIST + t], psv * dbg);
}

// ---------- K4a: S-build kernel (R7 build math verbatim -> bit-identical output).
// grid 2048 = (x, dt). 18 KB LDS -> 8 blocks/CU: load latency properly hidden,
// no stores competing. Dumps the finished st tile LINEARLY (16 B/lane) to ws.
__global__ __launch_bounds__(256) void k_states(float* __restrict__ ws) {
  __shared__ __align__(16) unsigned short st[8192];  // [e][d][g] swz, 16 KB
  __shared__ float sxl[576];                         // softs, stride-9 padded
  int x = blockIdx.x >> 3, dt = blockIdx.x & 7;
  int dBase = dt * 64;
  int t = threadIdx.x;

  {
    int i0 = t, i1 = t + 256;
    sxl[(i0 >> 3) * 9 + (i0 & 7)] = ws[WS_SOFTS + (size_t)x * 512 + i0];
    sxl[(i1 >> 3) * 9 + (i1 & 7)] = ws[WS_SOFTS + (size_t)x * 512 + i1];
  }
  __syncthreads();

  int dq = t & 15, gq = t >> 4;
#pragma unroll 1
  for (int e = 0; e < 2; ++e) {
    const unsigned short* ob =
        (const unsigned short*)(ws + WS_ONB) + (size_t)e * ONB_STRIDE + dBase + dq * 4;
    float av[4][4];
#pragma unroll
    for (int gg = 0; gg < 4; ++gg) {
      int g = gq * 4 + gg;
      float a0 = 0.f, a1 = 0.f, a2 = 0.f, a3 = 0.f;
      const unsigned short* rp = ob + (size_t)(g * 8) * 512;
#pragma unroll
      for (int n = 0; n < 8; ++n) {
        ushort4 vv = *(const ushort4*)(rp + (size_t)n * 512);
        float swv = sxl[g * 9 + n];
        a0 += swv * bf2f(vv.x);
        a1 += swv * bf2f(vv.y);
        a2 += swv * bf2f(vv.z);
        a3 += swv * bf2f(vv.w);
      }
      av[gg][0] = a0; av[gg][1] = a1; av[gg][2] = a2; av[gg][3] = a3;
    }
#pragma unroll
    for (int dd = 0; dd < 4; ++dd) {
      int d = dq * 4 + dd;
      ushort4 o = make_ushort4(f2bf(av[0][dd]), f2bf(av[1][dd]), f2bf(av[2][dd]), f2bf(av[3][dd]));
      *(ushort4*)&st[e * 4096 + ((d * 64 + gq * 4) ^ ((d & 7) << 3))] = o;
    }
  }
  __syncthreads();

  // linear dump: 16 KB, fully coalesced (16 B/lane)
  unsigned short* Sp = (unsigned short*)(ws + WS_S) + (size_t)blockIdx.x * 8192;
#pragma unroll
  for (int c = 0; c < 4; ++c)
    *(bf16x8*)&Sp[c * 2048 + t * 8] = *(const bf16x8*)&st[c * 2048 + t * 8];
}

// ---------- K4b: near-pure store kernel. stage psl + S (both linear, coalesced)
// -> one barrier -> MFMA -> uninterrupted stores (R7-proven tail). No VALU build,
// no latency chains ahead of the store stream.
__global__ __launch_bounds__(256) void k_quant2(const float* __restrict__ ws,
                                                float* __restrict__ out) {
  __shared__ __align__(16) unsigned short psl[16384];  // [b][g] swz, 32 KB
  __shared__ __align__(16) unsigned short st[8192];    // [e][d][g] swz, 16 KB
  int x = blockIdx.x >> 3, dt = blockIdx.x & 7;
  int dBase = dt * 64;
  int t = threadIdx.x, l = t & 63, w = t >> 6;
  int lr = l & 15, lh = l >> 4;

  // stage S tile: linear 16 B/lane reads (written by k_states same-bid -> same XCD L2)
  const unsigned short* Sp = (const unsigned short*)(ws + WS_S) + (size_t)blockIdx.x * 8192;
#pragma unroll
  for (int c = 0; c < 4; ++c)
    *(bf16x8*)&st[c * 2048 + t * 8] = *(const bf16x8*)&Sp[c * 2048 + t * 8];

  // stage ps into LDS (proven R2/R7 pattern)
  const unsigned short* psb = (const unsigned short*)(ws + WS_PSB);
#pragma unroll
  for (int c = 0; c < 8; ++c) {
    int cc = t + c * 256;
    int b = cc >> 3, gw8 = (cc & 7) * 8;
    bf16x8 v = *(const bf16x8*)(psb + (size_t)b * 64 + gw8);
    *(bf16x8*)&psl[(b * 64 + gw8) ^ ((b & 7) << 3)] = v;
  }
  __syncthreads();

  // bn frags from psl (proven R2/R7 pattern)
  bf16x8 bn[4][2];
#pragma unroll
  for (int j = 0; j < 4; ++j)
#pragma unroll
    for (int kk = 0; kk < 2; ++kk) {
      int b = w * 64 + j * 16 + lr;
      bn[j][kk] = *(const bf16x8*)&psl[(b * 64 + kk * 32 + lh * 8) ^ ((b & 7) << 3)];
    }

  // MFMA + store, both planes, NO barriers from here on
#pragma unroll 1
  for (int e = 0; e < 2; ++e) {
    bf16x8 am[4][2];
#pragma unroll
    for (int i = 0; i < 4; ++i)
#pragma unroll
      for (int kk = 0; kk < 2; ++kk)
        am[i][kk] = *(const bf16x8*)&st[e * 4096 +
                                        (((i * 16 + lr) * 64 + kk * 32 + lh * 8) ^ ((lr & 7) << 3))];

    f32x4 acc[4][4];
#pragma unroll
    for (int i = 0; i < 4; ++i)
#pragma unroll
      for (int j = 0; j < 4; ++j) {
        acc[i][j][0] = 0.f; acc[i][j][1] = 0.f; acc[i][j][2] = 0.f; acc[i][j][3] = 0.f;
      }
#pragma unroll
    for (int kk = 0; kk < 2; ++kk)
#pragma unroll
      for (int i = 0; i < 4; ++i)
#pragma unroll
        for (int j = 0; j < 4; ++j)
          acc[i][j] = __builtin_amdgcn_mfma_f32_16x16x32_bf16(am[i][kk], bn[j][kk], acc[i][j], 0, 0, 0);

    float* op = out + (e ? (size_t)OUT_QSIG : (size_t)OUT_QMU) + (size_t)x * (256 * 512);
#pragma unroll
    for (int i = 0; i < 4; ++i)
#pragma unroll
      for (int j = 0; j < 4; ++j) {
        size_t off = (size_t)(w * 64 + j * 16 + lr) * 512 + dBase + i * 16 + lh * 4;
        *(f32x4*)&op[off] = acc[i][j];
      }
  }
}

extern "C" void kernel_launch(void* const* d_in, const int* in_sizes, int n_in,
                              void* d_out, int out_size, void* d_ws, size_t ws_size,
                              hipStream_t stream) {
  (void)in_sizes; (void)n_in; (void)out_size; (void)ws_size;
  const float* mu = (const float*)d_in[0];
  const float* ls = (const float*)d_in[1];
  const float* on = (const float*)d_in[2];
  float* out = (float*)d_out;
  float* ws = (float*)d_ws;

  k_prep<<<dim3(768), dim3(256), 0, stream>>>(mu, ls, on, ws);
  k_dkb<<<dim3(256), dim3(256), 0, stream>>>(ws, out);
  k_sm<<<dim3(64), dim3(256), 0, stream>>>(ws, out);
  k_states<<<dim3(2048), dim3(256), 0, stream>>>(ws);
  k_quant2<<<dim3(2048), dim3(256), 0, stream>>>(ws, out);
}

// Round 13
// 75.045 us; speedup vs baseline: 1.1842x; 1.1842x over previous
//
#include <hip/hip_runtime.h>
#include <cstddef>
#include <cstdint>

typedef short bf16x8 __attribute__((ext_vector_type(8)));
typedef float f32x4 __attribute__((ext_vector_type(4)));

#define Bsz 256
#define Dsz 512
#define Gsz 64
#define Ksz 512

// ws float offsets
#define WS_DFLAT 0         // [512][256] f32
#define WS_SOFTS 131072    // [256][512] f32 (b-major, flat-k)
#define WS_BNORM 278528    // [256]
#define WS_CNORM 278784    // [512]
#define WS_PSB   279296    // [256][64] bf16, normal [b][g] order
#define WS_ONB   287488    // 2 planes [512][512] bf16
#define WS_ZB    549632    // 2 planes [256][512] bf16

#define ONB_STRIDE 262144  // ushorts per plane
#define ZB_STRIDE  131072  // ushorts per plane

// out float offsets
#define OUT_QMU  0
#define OUT_QSIG 33554432
#define OUT_DBG  67108864
#define OUT_DIST 67125248

__device__ __forceinline__ unsigned short f2bf(float f) {
  unsigned int u = __float_as_uint(f);
  u = (u + 0x7FFFu + ((u >> 16) & 1u)) >> 16;
  return (unsigned short)u;
}
__device__ __forceinline__ float bf2f(unsigned short h) {
  return __uint_as_float(((unsigned int)h) << 16);
}

// ---------- K1: prep (proven R2/R4/R7) ----------
__global__ __launch_bounds__(256) void k_prep(const float* __restrict__ mu,
                                              const float* __restrict__ ls,
                                              const float* __restrict__ on,
                                              float* __restrict__ ws) {
  int t = threadIdx.x;
  __shared__ float red[256];
  if (blockIdx.x < 512) {
    int k = blockIdx.x;
    float4 v = *(const float4*)(on + (size_t)k * 1024 + 4 * t);
    unsigned short* onb0 = (unsigned short*)(ws + WS_ONB);
    unsigned short* onb1 = onb0 + ONB_STRIDE;
    *(ushort2*)&onb0[(size_t)k * 512 + 2 * t] = make_ushort2(f2bf(v.x), f2bf(v.z));
    *(ushort2*)&onb1[(size_t)k * 512 + 2 * t] = make_ushort2(f2bf(v.y), f2bf(v.w));
    red[t] = v.x * v.x + v.y * v.y + v.z * v.z + v.w * v.w;
    __syncthreads();
    for (int off = 128; off > 0; off >>= 1) {
      if (t < off) red[t] += red[t + off];
      __syncthreads();
    }
    if (t == 0) ws[WS_CNORM + k] = red[0];
  } else {
    int b = blockIdx.x - 512;
    unsigned short* zb0 = (unsigned short*)(ws + WS_ZB);
    unsigned short* zb1 = zb0 + ZB_STRIDE;
    float part = 0.f;
    for (int d = t; d < Dsz; d += 256) {
      float m = mu[b * Dsz + d];
      float s = expf(ls[b * Dsz + d]);
      zb0[(size_t)b * 512 + d] = f2bf(m);
      zb1[(size_t)b * 512 + d] = f2bf(s);
      part += m * m + s * s;
    }
    red[t] = part;
    __syncthreads();
    for (int off = 128; off > 0; off >>= 1) {
      if (t < off) red[t] += red[t + off];
      __syncthreads();
    }
    if (t == 0) ws[WS_BNORM + b] = red[0];
  }
}

// ---------- K2: d_kb via bf16 MFMA (proven R4/R7) ----------
__global__ __launch_bounds__(256) void k_dkb(float* __restrict__ ws,
                                             float* __restrict__ out) {
  __shared__ float pl[4][16][33];
  int t = threadIdx.x, l = t & 63, w = t >> 6;
  int lr = l & 15, lh = l >> 4;
  if (blockIdx.x == 0) out[OUT_DIST + t] = 0.f;
  int kt = blockIdx.x >> 3, bt = blockIdx.x & 7;
  int k0 = kt * 16, b0 = bt * 32;
  const unsigned short* Ap =
      (const unsigned short*)(ws + WS_ONB) + (size_t)(w >> 1) * ONB_STRIDE + (size_t)k0 * 512;
  const unsigned short* Bp =
      (const unsigned short*)(ws + WS_ZB) + (size_t)(w >> 1) * ZB_STRIDE + (size_t)b0 * 512;
  int dbase = (w & 1) * 256;

  f32x4 acc[2];
#pragma unroll
  for (int j = 0; j < 2; ++j) { acc[j][0] = 0.f; acc[j][1] = 0.f; acc[j][2] = 0.f; acc[j][3] = 0.f; }

#pragma unroll
  for (int kk = 0; kk < 8; ++kk) {
    int dl = dbase + kk * 32 + lh * 8;
    bf16x8 a0 = *(const bf16x8*)(Ap + (size_t)lr * 512 + dl);
    bf16x8 q0 = *(const bf16x8*)(Bp + (size_t)lr * 512 + dl);
    bf16x8 q1 = *(const bf16x8*)(Bp + (size_t)(lr + 16) * 512 + dl);
    acc[0] = __builtin_amdgcn_mfma_f32_16x16x32_bf16(a0, q0, acc[0], 0, 0, 0);
    acc[1] = __builtin_amdgcn_mfma_f32_16x16x32_bf16(a0, q1, acc[1], 0, 0, 0);
  }

#pragma unroll
  for (int j = 0; j < 2; ++j)
#pragma unroll
    for (int r = 0; r < 4; ++r)
      pl[w][lh * 4 + r][j * 16 + lr] = acc[j][r];
  __syncthreads();

  int r = t >> 4, c = (t & 15) * 2;
  float s0 = pl[0][r][c] + pl[1][r][c] + pl[2][r][c] + pl[3][r][c];
  float s1 = pl[0][r][c + 1] + pl[1][r][c + 1] + pl[2][r][c + 1] + pl[3][r][c + 1];
  float cn = ws[WS_CNORM + k0 + r];
  float2 o = make_float2(cn + ws[WS_BNORM + b0 + c] - 2.f * s0,
                         cn + ws[WS_BNORM + b0 + c + 1] - 2.f * s1);
  *(float2*)&ws[WS_DFLAT + (size_t)(k0 + r) * 256 + b0 + c] = o;
}

// ---------- K3: fused softmaxes + dist atomics (proven R7) ----------
__global__ __launch_bounds__(256) void k_sm(float* __restrict__ ws,
                                            float* __restrict__ out) {
  int g = blockIdx.x, t = threadIdx.x;
  const float* df = ws + WS_DFLAT;
  int k = 2 * t + (g >> 5);
  int col = (g & 31) << 3;
  const float* p = df + (size_t)k * 256 + col;
  float4 v0 = *(const float4*)p;
  float4 v1 = *(const float4*)(p + 4);
  float d[8] = {v0.x, v0.y, v0.z, v0.w, v1.x, v1.y, v1.z, v1.w};
  float m = d[0];
#pragma unroll
  for (int n = 1; n < 8; ++n) m = fminf(m, d[n]);
  float wv[8], s = 0.f, wd = 0.f;
#pragma unroll
  for (int n = 0; n < 8; ++n) {
    wv[n] = expf(m - d[n]);
    s += wv[n];
    wd += wv[n] * d[n];
  }
  float inv = 1.f / s;
  float* so = ws + WS_SOFTS + (size_t)t * 512 + g * 8;
  *(float4*)so = make_float4(wv[0] * inv, wv[1] * inv, wv[2] * inv, wv[3] * inv);
  *(float4*)(so + 4) = make_float4(wv[4] * inv, wv[5] * inv, wv[6] * inv, wv[7] * inv);
  float dbg = wd * inv;
  out[OUT_DBG + t * 64 + g] = dbg;

  __shared__ float red[256];
  red[t] = dbg;
  __syncthreads();
  for (int off = 128; off > 0; off >>= 1) {
    if (t < off) red[t] = fminf(red[t], red[t + off]);
    __syncthreads();
  }
  float mm = red[0];
  __syncthreads();
  float wp = expf(mm - dbg);
  red[t] = wp;
  __syncthreads();
  for (int off = 128; off > 0; off >>= 1) {
    if (t < off) red[t] += red[t + off];
    __syncthreads();
  }
  float psv = wp / red[0];
  ((unsigned short*)(ws + WS_PSB))[t * 64 + g] = f2bf(psv);
  atomicAdd(&out[OUT_DIST + t], psv * dbg);
}

// ---------- K4: quantised_{mu,sig}. Exact R7 structure; ONLY change: store
// loops swapped to j-outer/i-inner so consecutive store instructions complete
// each 128 B line back-to-back (i=0,1 write the two 64 B halves of the same
// lines for the same 16 rows) -> 4x fewer open half-lines per wave.
__global__ __launch_bounds__(256) void k_quant(const float* __restrict__ ws,
                                               float* __restrict__ out) {
  __shared__ __align__(16) unsigned short psl[16384];   // [b][g] swz, 32 KB
  __shared__ __align__(16) unsigned short st[2][4096];  // [e][d][g] swz, 16 KB
  __shared__ float sxl[576];                            // softs, stride-9 padded
  int x = blockIdx.x >> 3, dt = blockIdx.x & 7;
  int dBase = dt * 64;
  int t = threadIdx.x, l = t & 63, w = t >> 6;
  int lr = l & 15, lh = l >> 4;

  // stage ps into LDS (proven R2/R7 pattern)
  const unsigned short* psb = (const unsigned short*)(ws + WS_PSB);
#pragma unroll
  for (int c = 0; c < 8; ++c) {
    int cc = t + c * 256;  // 0..2047 chunks of 8 ushorts
    int b = cc >> 3, gw8 = (cc & 7) * 8;
    bf16x8 v = *(const bf16x8*)(psb + (size_t)b * 64 + gw8);
    *(bf16x8*)&psl[(b * 64 + gw8) ^ ((b & 7) << 3)] = v;
  }
  {
    int i0 = t, i1 = t + 256;
    sxl[(i0 >> 3) * 9 + (i0 & 7)] = ws[WS_SOFTS + (size_t)x * 512 + i0];
    sxl[(i1 >> 3) * 9 + (i1 & 7)] = ws[WS_SOFTS + (size_t)x * 512 + i1];
  }
  __syncthreads();

  // build S_T for BOTH planes (proven R4/R7): thread owns 4 d x 4 g
  int dq = t & 15, gq = t >> 4;
#pragma unroll 1
  for (int e = 0; e < 2; ++e) {
    const unsigned short* ob =
        (const unsigned short*)(ws + WS_ONB) + (size_t)e * ONB_STRIDE + dBase + dq * 4;
    float av[4][4];
#pragma unroll
    for (int gg = 0; gg < 4; ++gg) {
      int g = gq * 4 + gg;
      float a0 = 0.f, a1 = 0.f, a2 = 0.f, a3 = 0.f;
      const unsigned short* rp = ob + (size_t)(g * 8) * 512;
#pragma unroll
      for (int n = 0; n < 8; ++n) {
        ushort4 vv = *(const ushort4*)(rp + (size_t)n * 512);
        float swv = sxl[g * 9 + n];
        a0 += swv * bf2f(vv.x);
        a1 += swv * bf2f(vv.y);
        a2 += swv * bf2f(vv.z);
        a3 += swv * bf2f(vv.w);
      }
      av[gg][0] = a0; av[gg][1] = a1; av[gg][2] = a2; av[gg][3] = a3;
    }
#pragma unroll
    for (int dd = 0; dd < 4; ++dd) {
      int d = dq * 4 + dd;
      ushort4 o = make_ushort4(f2bf(av[0][dd]), f2bf(av[1][dd]), f2bf(av[2][dd]), f2bf(av[3][dd]));
      *(ushort4*)&st[e][(d * 64 + gq * 4) ^ ((d & 7) << 3)] = o;
    }
  }
  __syncthreads();

  // bn frags from psl (proven R2/R7 pattern)
  bf16x8 bn[4][2];
#pragma unroll
  for (int j = 0; j < 4; ++j)
#pragma unroll
    for (int kk = 0; kk < 2; ++kk) {
      int b = w * 64 + j * 16 + lr;
      bn[j][kk] = *(const bf16x8*)&psl[(b * 64 + kk * 32 + lh * 8) ^ ((b & 7) << 3)];
    }

  // MFMA + store, both planes, NO barriers from here on
#pragma unroll 1
  for (int e = 0; e < 2; ++e) {
    bf16x8 am[4][2];
#pragma unroll
    for (int i = 0; i < 4; ++i)
#pragma unroll
      for (int kk = 0; kk < 2; ++kk)
        am[i][kk] = *(const bf16x8*)&st[e][((i * 16 + lr) * 64 + kk * 32 + lh * 8) ^ ((lr & 7) << 3)];

    f32x4 acc[4][4];
#pragma unroll
    for (int i = 0; i < 4; ++i)
#pragma unroll
      for (int j = 0; j < 4; ++j) {
        acc[i][j][0] = 0.f; acc[i][j][1] = 0.f; acc[i][j][2] = 0.f; acc[i][j][3] = 0.f;
      }
#pragma unroll
    for (int kk = 0; kk < 2; ++kk)
#pragma unroll
      for (int i = 0; i < 4; ++i)
#pragma unroll
        for (int j = 0; j < 4; ++j)
          acc[i][j] = __builtin_amdgcn_mfma_f32_16x16x32_bf16(am[i][kk], bn[j][kk], acc[i][j], 0, 0, 0);

    float* op = out + (e ? (size_t)OUT_QSIG : (size_t)OUT_QMU) + (size_t)x * (256 * 512);
#pragma unroll
    for (int j = 0; j < 4; ++j)   // j OUTER: same 16 rows across inner i
#pragma unroll
      for (int i = 0; i < 4; ++i) {  // i INNER: d halves complete lines back-to-back
        size_t off = (size_t)(w * 64 + j * 16 + lr) * 512 + dBase + i * 16 + lh * 4;
        *(f32x4*)&op[off] = acc[i][j];
      }
  }
}

extern "C" void kernel_launch(void* const* d_in, const int* in_sizes, int n_in,
                              void* d_out, int out_size, void* d_ws, size_t ws_size,
                              hipStream_t stream) {
  (void)in_sizes; (void)n_in; (void)out_size; (void)ws_size;
  const float* mu = (const float*)d_in[0];
  const float* ls = (const float*)d_in[1];
  const float* on = (const float*)d_in[2];
  float* out = (float*)d_out;
  float* ws = (float*)d_ws;

  k_prep<<<dim3(768), dim3(256), 0, stream>>>(mu, ls, on, ws);
  k_dkb<<<dim3(256), dim3(256), 0, stream>>>(ws, out);
  k_sm<<<dim3(64), dim3(256), 0, stream>>>(ws, out);
  k_quant<<<dim3(2048), dim3(256), 0, stream>>>(ws, out);
}